// Round 5
// baseline (142.332 us; speedup 1.0000x reference)
//
#include <hip/hip_runtime.h>

#define TEMP 0.05f
#define EPS 1e-8f
#define NROWS 16384
#define DDIM 1024

typedef float f32x4 __attribute__((ext_vector_type(4)));

// One row per 256-thread block: each thread loads exactly one float4 from a
// and one from b (256 threads x 4 floats = 1024 = D). Minimal serial chain,
// maximal block-level concurrency (16384 blocks, ~8 resident/CU, ~64 queued).
__global__ __launch_bounds__(256) void byol_row_kernel(
        const float* __restrict__ a, const float* __restrict__ b,
        float* __restrict__ partials) {
    const int row  = blockIdx.x;
    const int t    = threadIdx.x;
    const int wave = t >> 6;
    const int lane = t & 63;

    const f32x4* a4 = (const f32x4*)(a) + (size_t)row * (DDIM / 4) + t;
    const f32x4* b4 = (const f32x4*)(b) + (size_t)row * (DDIM / 4) + t;

    f32x4 av = *a4;
    f32x4 bv = *b4;

    float dot = av.x * bv.x + av.y * bv.y + av.z * bv.z + av.w * bv.w;
    float aa  = av.x * av.x + av.y * av.y + av.z * av.z + av.w * av.w;
    float bb  = bv.x * bv.x + bv.y * bv.y + bv.z * bv.z + bv.w * bv.w;

    // Wave-level butterfly (6 steps x 3 values).
#pragma unroll
    for (int off = 32; off > 0; off >>= 1) {
        dot += __shfl_xor(dot, off, 64);
        aa  += __shfl_xor(aa,  off, 64);
        bb  += __shfl_xor(bb,  off, 64);
    }

    // Cross-wave combine via LDS (4 waves).
    __shared__ float s[12];
    if (lane == 0) {
        s[wave]     = dot;
        s[wave + 4] = aa;
        s[wave + 8] = bb;
    }
    __syncthreads();
    if (t == 0) {
        float d = s[0] + s[1] + s[2]  + s[3];
        float x = s[4] + s[5] + s[6]  + s[7];
        float y = s[8] + s[9] + s[10] + s[11];
        float n1 = fmaxf(sqrtf(x), EPS);
        float n2 = fmaxf(sqrtf(y), EPS);
        partials[row] = 2.0f - 2.0f * (d / (n1 * n2));
    }
}

__global__ __launch_bounds__(256) void byol_final_kernel(
        const float* __restrict__ partials, float* __restrict__ out) {
    float sum = 0.f;
#pragma unroll
    for (int j = 0; j < NROWS / 256; ++j)
        sum += partials[threadIdx.x + 256 * j];

#pragma unroll
    for (int off = 32; off > 0; off >>= 1)
        sum += __shfl_down(sum, off, 64);

    __shared__ float s[4];
    const int wave = threadIdx.x >> 6;
    const int lane = threadIdx.x & 63;
    if (lane == 0) s[wave] = sum;
    __syncthreads();
    if (threadIdx.x == 0) {
        out[0] = (s[0] + s[1] + s[2] + s[3]) * (1.0f / ((float)NROWS * TEMP));
    }
}

extern "C" void kernel_launch(void* const* d_in, const int* in_sizes, int n_in,
                              void* d_out, int out_size, void* d_ws, size_t ws_size,
                              hipStream_t stream) {
    const float* a = (const float*)d_in[0];
    const float* b = (const float*)d_in[1];
    float* out = (float*)d_out;
    float* partials = (float*)d_ws;   // NROWS floats = 64 KB

    byol_row_kernel<<<NROWS, 256, 0, stream>>>(a, b, partials);
    byol_final_kernel<<<1, 256, 0, stream>>>(partials, out);
}